// Round 1
// baseline (1221.787 us; speedup 1.0000x reference)
//
#include <hip/hip_runtime.h>

#define NROWS 1048576
#define DIM   128
#define NCLS  1000
#define MOM   0.95f

// ---------------------------------------------------------------------------
// Phase 1: weighted per-class segment sum.
// Grid: 256 blocks = 4 column-groups x 64 row-chunks, 512 threads (8 waves),
// 1 block/CU (132 KB LDS). Each block privatizes [1000][32] f32 in LDS.
// Column index rotated by label to break the stride-4 LDS bank pattern.
// ---------------------------------------------------------------------------
__global__ __launch_bounds__(512) void proto_phase1(
        const float* __restrict__ feats,
        const int*   __restrict__ labels,
        const float* __restrict__ weights,
        float* __restrict__ accF,   // [NCLS][DIM]
        float* __restrict__ accW)   // [NCLS]
{
    __shared__ float sA[NCLS][32];   // 128000 B
    __shared__ float sW[NCLS];       //   4000 B

    const int tid   = threadIdx.x;
    const int g     = blockIdx.x & 3;       // column group: cols [g*32, g*32+32)
    const int chunk = blockIdx.x >> 2;      // row chunk: 0..63
    const int c0    = g * 32;

    for (int i = tid; i < NCLS * 32; i += 512) ((float*)sA)[i] = 0.f;
    for (int i = tid; i < NCLS;      i += 512) sW[i] = 0.f;
    __syncthreads();

    const int lane8 = tid & 7;              // which float4 of the 32-col chunk
    const int rOff  = tid >> 3;             // 0..63 rows per block-iteration
    const long base = (long)chunk * (NROWS / 64);   // 16384 rows per chunk
    const float4* __restrict__ f4 = (const float4*)feats;  // row stride = 32 float4
    const int f4c = (c0 >> 2) + lane8;

    // 16384 rows / 64 rows-per-iter = 256 iterations, unrolled x4
    for (int it = 0; it < 256; it += 4) {
        float4 f[4]; int lab[4]; float w[4];
#pragma unroll
        for (int u = 0; u < 4; ++u) {
            long r = base + (long)(it + u) * 64 + rOff;
            f[u]   = f4[r * 32 + f4c];
            lab[u] = labels[r];
            w[u]   = weights[r];
        }
#pragma unroll
        for (int u = 0; u < 4; ++u) {
            const int   l  = lab[u];
            const float wu = w[u];
            const int   cb = lane8 * 4;
            unsafeAtomicAdd(&sA[l][(cb + 0 + l) & 31], wu * f[u].x);
            unsafeAtomicAdd(&sA[l][(cb + 1 + l) & 31], wu * f[u].y);
            unsafeAtomicAdd(&sA[l][(cb + 2 + l) & 31], wu * f[u].z);
            unsafeAtomicAdd(&sA[l][(cb + 3 + l) & 31], wu * f[u].w);
            if (g == 0 && lane8 == 0) unsafeAtomicAdd(&sW[l], wu);
        }
    }
    __syncthreads();

    // Flush LDS partials to global accumulators (un-rotate columns).
    for (int i = tid; i < NCLS * 32; i += 512) {
        const int l  = i >> 5;
        const int cp = i & 31;
        const int c  = (cp - l) & 31;
        unsafeAtomicAdd(&accF[l * DIM + c0 + c], sA[l][cp]);
    }
    if (g == 0) {
        for (int i = tid; i < NCLS; i += 512) unsafeAtomicAdd(&accW[i], sW[i]);
    }
}

// ---------------------------------------------------------------------------
// Phase 2: EMA blend into output.
// ---------------------------------------------------------------------------
__global__ __launch_bounds__(256) void proto_phase2(
        const float* __restrict__ proto,
        const float* __restrict__ accF,
        const float* __restrict__ accW,
        float* __restrict__ out)
{
    const int i = blockIdx.x * 256 + threadIdx.x;
    if (i >= NCLS * DIM) return;
    const int   l  = i >> 7;                 // DIM = 128
    const float ws = accW[l];
    const float p  = proto[i];
    out[i] = (ws > 0.f) ? (MOM * p + (1.f - MOM) * (accF[i] / fmaxf(ws, 1e-8f)))
                        : p;
}

extern "C" void kernel_launch(void* const* d_in, const int* in_sizes, int n_in,
                              void* d_out, int out_size, void* d_ws, size_t ws_size,
                              hipStream_t stream)
{
    const float* feats   = (const float*)d_in[0];
    const int*   labels  = (const int*)  d_in[1];
    const float* weights = (const float*)d_in[2];
    const float* proto   = (const float*)d_in[3];
    float* out  = (float*)d_out;
    float* accF = (float*)d_ws;              // NCLS*DIM floats
    float* accW = accF + NCLS * DIM;         // NCLS floats

    hipMemsetAsync(d_ws, 0, (size_t)(NCLS * DIM + NCLS) * sizeof(float), stream);
    proto_phase1<<<256, 512, 0, stream>>>(feats, labels, weights, accF, accW);
    proto_phase2<<<(NCLS * DIM + 255) / 256, 256, 0, stream>>>(proto, accF, accW, out);
}

// Round 8
// 716.069 us; speedup vs baseline: 1.7062x; 1.7062x over previous
//
#include <hip/hip_runtime.h>

#define NROWS 1048576
#define DIM   128
#define NCLS  1000
#define RPB   4096          // rows per block in hist/scatter (NROWS/256)
#define RPT   16            // rows per thread (RPB/256)
#define MOM   0.95f

// ws layout (u32): total[1024] | classBase[1024] | cursor[1024] | perm[NROWS]
// total ~4.2 MB of d_ws. Only total[] needs zeroing per call.

// ---------------------------------------------------------------------------
// K1: per-block LDS histogram of labels -> global total[c]
// ---------------------------------------------------------------------------
__global__ __launch_bounds__(256) void k_hist(const int* __restrict__ labels,
                                              unsigned* __restrict__ total)
{
    __shared__ unsigned h[NCLS];
    const int tid = threadIdx.x;
    for (int c = tid; c < NCLS; c += 256) h[c] = 0u;
    __syncthreads();
    const int base = blockIdx.x * RPB;
#pragma unroll
    for (int k = 0; k < RPT; ++k)
        atomicAdd(&h[labels[base + k * 256 + tid]], 1u);
    __syncthreads();
    for (int c = tid; c < NCLS; c += 256)
        if (h[c]) atomicAdd(&total[c], h[c]);
}

// ---------------------------------------------------------------------------
// K2: single-block exclusive scan over total -> classBase, cursor
// ---------------------------------------------------------------------------
__global__ __launch_bounds__(1024) void k_scan(const unsigned* __restrict__ total,
                                               unsigned* __restrict__ classBase,
                                               unsigned* __restrict__ cursor)
{
    __shared__ unsigned s[1024];
    const int tid = threadIdx.x;
    unsigned v = (tid < NCLS) ? total[tid] : 0u;
    s[tid] = v;
    __syncthreads();
    for (int off = 1; off < 1024; off <<= 1) {
        unsigned u = (tid >= off) ? s[tid - off] : 0u;
        __syncthreads();
        s[tid] += u;
        __syncthreads();
    }
    if (tid < NCLS) {
        unsigned excl = s[tid] - v;   // exclusive prefix
        classBase[tid] = excl;
        cursor[tid]    = excl;
    }
}

// ---------------------------------------------------------------------------
// K3: counting-sort scatter. Per-block class counts (LDS), one global
// atomicAdd per present class for the block's base, LDS atomic-rtn for
// per-element offsets. perm[pos] = row index, grouped by class.
// ---------------------------------------------------------------------------
__global__ __launch_bounds__(256) void k_scatter(const int* __restrict__ labels,
                                                 unsigned* __restrict__ cursor,
                                                 unsigned* __restrict__ perm)
{
    __shared__ unsigned h[NCLS];
    __shared__ unsigned basec[NCLS];
    const int tid = threadIdx.x;
    for (int c = tid; c < NCLS; c += 256) h[c] = 0u;
    __syncthreads();
    const int base = blockIdx.x * RPB;
    int lab[RPT];
#pragma unroll
    for (int k = 0; k < RPT; ++k) {
        lab[k] = labels[base + k * 256 + tid];
        atomicAdd(&h[lab[k]], 1u);
    }
    __syncthreads();
    for (int c = tid; c < NCLS; c += 256) {
        unsigned cnt = h[c];
        if (cnt) basec[c] = atomicAdd(&cursor[c], cnt);
        h[c] = 0u;                      // reuse as running offset
    }
    __syncthreads();
#pragma unroll
    for (int k = 0; k < RPT; ++k) {
        const int c = lab[k];
        unsigned off = atomicAdd(&h[c], 1u);
        perm[basec[c] + off] = (unsigned)(base + k * 256 + tid);
    }
}

// ---------------------------------------------------------------------------
// K4: one block per class. Gather rows via perm (512B contiguous per row,
// 32 lanes x float4), register-accumulate across 8 row-groups, LDS tree
// reduce, fused EMA epilogue. No atomics.
// ---------------------------------------------------------------------------
__global__ __launch_bounds__(256) void k_reduce(
        const float*    __restrict__ feats,
        const float*    __restrict__ weights,
        const float*    __restrict__ proto,
        const unsigned* __restrict__ perm,
        const unsigned* __restrict__ total,
        const unsigned* __restrict__ classBase,
        float* __restrict__ out)
{
    const int c      = blockIdx.x;
    const int tid    = threadIdx.x;
    const int lane32 = tid & 31;
    const int grp    = tid >> 5;            // 0..7 row-groups
    const int n      = (int)total[c];
    const unsigned base = classBase[c];
    const float4* __restrict__ f4 = (const float4*)feats;

    float4 acc = make_float4(0.f, 0.f, 0.f, 0.f);
    float  wacc = 0.f;

    int i = grp;
    // 4x unrolled: 4 independent perm->w/f4 chains in flight per thread
    for (; i + 24 < n; i += 32) {
        unsigned r0 = perm[base + i];
        unsigned r1 = perm[base + i + 8];
        unsigned r2 = perm[base + i + 16];
        unsigned r3 = perm[base + i + 24];
        float w0 = weights[r0], w1 = weights[r1];
        float w2 = weights[r2], w3 = weights[r3];
        float4 f0 = f4[(long)r0 * 32 + lane32];
        float4 f1 = f4[(long)r1 * 32 + lane32];
        float4 f2 = f4[(long)r2 * 32 + lane32];
        float4 f3 = f4[(long)r3 * 32 + lane32];
        acc.x += w0 * f0.x; acc.y += w0 * f0.y; acc.z += w0 * f0.z; acc.w += w0 * f0.w;
        acc.x += w1 * f1.x; acc.y += w1 * f1.y; acc.z += w1 * f1.z; acc.w += w1 * f1.w;
        acc.x += w2 * f2.x; acc.y += w2 * f2.y; acc.z += w2 * f2.z; acc.w += w2 * f2.w;
        acc.x += w3 * f3.x; acc.y += w3 * f3.y; acc.z += w3 * f3.z; acc.w += w3 * f3.w;
        wacc += w0 + w1 + w2 + w3;
    }
    for (; i < n; i += 8) {
        unsigned r = perm[base + i];
        float w = weights[r];
        float4 f = f4[(long)r * 32 + lane32];
        acc.x += w * f.x; acc.y += w * f.y; acc.z += w * f.z; acc.w += w * f.w;
        wacc += w;
    }

    __shared__ float4 sAcc[8][32];
    __shared__ float  sW[8];
    sAcc[grp][lane32] = acc;
    if (lane32 == 0) sW[grp] = wacc;   // identical across lanes of the group
    __syncthreads();

    if (grp == 0) {
        float4 t = sAcc[0][lane32];
#pragma unroll
        for (int g = 1; g < 8; ++g) {
            float4 a = sAcc[g][lane32];
            t.x += a.x; t.y += a.y; t.z += a.z; t.w += a.w;
        }
        float ws = 0.f;
#pragma unroll
        for (int g = 0; g < 8; ++g) ws += sW[g];

        const float4 p = ((const float4*)proto)[c * 32 + lane32];
        float4 o;
        if (ws > 0.f) {
            const float den = fmaxf(ws, 1e-8f);
            o.x = MOM * p.x + 0.05f * (t.x / den);
            o.y = MOM * p.y + 0.05f * (t.y / den);
            o.z = MOM * p.z + 0.05f * (t.z / den);
            o.w = MOM * p.w + 0.05f * (t.w / den);
        } else {
            o = p;
        }
        ((float4*)out)[c * 32 + lane32] = o;
    }
}

extern "C" void kernel_launch(void* const* d_in, const int* in_sizes, int n_in,
                              void* d_out, int out_size, void* d_ws, size_t ws_size,
                              hipStream_t stream)
{
    const float* feats   = (const float*)d_in[0];
    const int*   labels  = (const int*)  d_in[1];
    const float* weights = (const float*)d_in[2];
    const float* proto   = (const float*)d_in[3];
    float* out = (float*)d_out;

    unsigned* total     = (unsigned*)d_ws;
    unsigned* classBase = total + 1024;
    unsigned* cursor    = classBase + 1024;
    unsigned* perm      = cursor + 1024;

    hipMemsetAsync(total, 0, 1024 * sizeof(unsigned), stream);
    k_hist   <<<256, 256, 0, stream>>>(labels, total);
    k_scan   <<<1, 1024, 0, stream>>>(total, classBase, cursor);
    k_scatter<<<256, 256, 0, stream>>>(labels, cursor, perm);
    k_reduce <<<NCLS, 256, 0, stream>>>(feats, weights, proto, perm,
                                        total, classBase, out);
}